// Round 1
// 196.887 us; speedup vs baseline: 1.0229x; 1.0229x over previous
//
#include <hip/hip_runtime.h>

// DirectionalProcessor: out[b,y,x,o] = bc[o] + sum_{d,c} g[b,y-dy_d,x-dx_d,c] * M_d[c,o]
// with M_d[c,o] = sum_e Wd[d,c,e]*Wc[o,d*256+e]  (folded -> 68.7 GFLOP implicit GEMM
// [65536 x 2048] @ [2048 x 256], B,H,W,C=16,64,64,256, 8 dirs).
//
// R6: 256x256 tile, 8 waves (2M x 4N), 512 threads, grid 256 (1 block/CU).
// R5 (128^2, 4 blocks/CU) sat at MfmaUtil 36% ~= the 128^2-structure ceiling:
// only 16 MFMA per wave per vmcnt(2)+s_barrier interval, ~1750 cy/iter of sync
// overhead per CU. Now 32 MFMA/wave/interval, BN=256 so A is fetched once
// (FETCH should drop ~59->~42 MB), B-frag L2 traffic per FLOP halved, A-DMA
// flight doubled in cycles at the same vmcnt count. FIFO proof unchanged from
// R5: queue at the wait is [A(kt+1)x2, B(kt+1)x4, A(kt+2)x2]; vmcnt(2) retires
// exactly the first six. XCD swizzle: each XCD owns 2 images (~4.5 MB ~ its L2).

typedef unsigned short u16;
typedef unsigned int u32;
typedef __attribute__((ext_vector_type(8))) short bf16x8;   // 8 x bf16 = 4 VGPRs
typedef __attribute__((ext_vector_type(4))) float f32x4;

#define GP_BYTES 35684352    // 16*66*66*256 * 2

__device__ __forceinline__ u16 f2bf(float f) {   // RNE f32->bf16
  u32 u = __float_as_uint(f);
  u32 r = u + 0x7fffu + ((u >> 16) & 1u);
  return (u16)(r >> 16);
}
__device__ __forceinline__ u32 pack2(float a, float b) {
  return (u32)f2bf(a) | ((u32)f2bf(b) << 16);
}

// ---------------- kernel 1: zero-padded bf16 copy of g ----------------
__global__ __launch_bounds__(256) void pad_convert(const float* __restrict__ g,
                                                   u16* __restrict__ gp) {
  int id = blockIdx.x * 256 + threadIdx.x;      // one thread per 8 channels
  if (id >= 2230272) return;                    // 16*66*66*32
  int c8 = id & 31;
  int t = id >> 5;
  int xx = t % 66;
  int s = t / 66;
  int yy = s % 66;
  int b  = s / 66;
  u32 o0 = 0, o1 = 0, o2 = 0, o3 = 0;
  if (yy != 0 && yy != 65 && xx != 0 && xx != 65) {
    const float* src = g + ((((b << 6) + yy - 1) << 6) + xx - 1) * 256 + (c8 << 3);
    float4 fa = *(const float4*)src;
    float4 fb = *(const float4*)(src + 4);
    o0 = pack2(fa.x, fa.y);
    o1 = pack2(fa.z, fa.w);
    o2 = pack2(fb.x, fb.y);
    o3 = pack2(fb.z, fb.w);
  }
  uint4 v; v.x = o0; v.y = o1; v.z = o2; v.w = o3;
  *(uint4*)(gp + (size_t)id * 8) = v;
}

// ---------------- kernel 2: MFMA weight fold into fragment-ordered Bf ----------------
// Bf u16 index: ((d*8 + c32)*16 + o16)*512 + lane*8 + e, where lane = (o&15) + ((c>>3)&3)*16
// holds M_d[c = c32*32 + (lane>>4)*8 + e][o = o16*16 + (lane&15)]  (B-operand frag order).
__global__ __launch_bounds__(256) void build_mt(const float* __restrict__ Wd,
                                                const float* __restrict__ Wc,
                                                u16* __restrict__ Bf) {
  __shared__ __align__(16) u16 As[128 * 32];
  __shared__ __align__(16) u16 Bs[128 * 32];
  const int bid = blockIdx.x;          // 32 blocks: 2 n-tiles x (8 d x 2 c-halves)
  const int n0    = (bid & 1) << 7;
  const int mblk  = bid >> 1;          // 0..15
  const int d     = mblk >> 1;
  const int chalf = (mblk & 1) << 7;
  const int tid  = threadIdx.x;
  const int lane = tid & 63, wid = tid >> 6;
  const int wm = (wid >> 1) << 6, wn = (wid & 1) << 6;
  const int quad = lane >> 4, r16 = lane & 15;
  const int srow = tid >> 1, hh = tid & 1;
  const int swz  = (srow >> 1) & 3;
  const int ssl  = (quad ^ ((r16 >> 1) & 3)) << 3;
  f32x4 acc[4][4] = {};

  for (int e0 = 0; e0 < 256; e0 += 32) {
    __syncthreads();
    const float* pa = Wd + (size_t)(d * 256 + chalf + srow) * 256 + e0 + hh * 16;
    const float* pb = Wc + (size_t)(n0 + srow) * 2048 + d * 256 + e0 + hh * 16;
#pragma unroll
    for (int i = 0; i < 2; ++i) {
      float4 a0 = *(const float4*)(pa + i * 8);
      float4 a1 = *(const float4*)(pa + i * 8 + 4);
      float4 b0 = *(const float4*)(pb + i * 8);
      float4 b1 = *(const float4*)(pb + i * 8 + 4);
      uint4 va, vb;
      va.x = pack2(a0.x, a0.y); va.y = pack2(a0.z, a0.w);
      va.z = pack2(a1.x, a1.y); va.w = pack2(a1.z, a1.w);
      vb.x = pack2(b0.x, b0.y); vb.y = pack2(b0.z, b0.w);
      vb.z = pack2(b1.x, b1.y); vb.w = pack2(b1.z, b1.w);
      int slot = (2 * hh + i) ^ swz;
      *(uint4*)&As[srow * 32 + slot * 8] = va;
      *(uint4*)&Bs[srow * 32 + slot * 8] = vb;
    }
    __syncthreads();
    bf16x8 bfr[4];
#pragma unroll
    for (int nt = 0; nt < 4; ++nt)
      bfr[nt] = *(const bf16x8*)&Bs[(wn + nt * 16 + r16) * 32 + ssl];
#pragma unroll
    for (int mt = 0; mt < 4; ++mt) {
      bf16x8 af = *(const bf16x8*)&As[(wm + mt * 16 + r16) * 32 + ssl];
#pragma unroll
      for (int nt = 0; nt < 4; ++nt)
        acc[mt][nt] = __builtin_amdgcn_mfma_f32_16x16x32_bf16(af, bfr[nt], acc[mt][nt], 0, 0, 0);
    }
  }
  // scatter into fragment-ordered Bf (C/D layout: col=o=r16-based, row=c=quad*4+reg)
#pragma unroll
  for (int mt = 0; mt < 4; ++mt) {
#pragma unroll
    for (int nt = 0; nt < 4; ++nt) {
      const int o = n0 + wn + nt * 16 + r16;
      f32x4 v = acc[mt][nt];
#pragma unroll
      for (int r = 0; r < 4; ++r) {
        const int c = chalf + wm + mt * 16 + quad * 4 + r;
        const int lane2 = (o & 15) + (((c >> 3) & 3) << 4);
        const size_t idx = ((size_t)((d * 8 + (c >> 5)) * 16 + (o >> 4)) * 512) + lane2 * 8 + (c & 7);
        Bf[idx] = f2bf(v[r]);
      }
    }
  }
}

// ---------------- kernel 3: main implicit-GEMM conv ----------------
// directions (dx,dy) -> source offset (ox,oy)=(-dx,-dy); DOFF = (oy*66+ox)*256 in gp elems
__constant__ int DOFF[8] = {16896, 16640, -256, -17152, -16896, -16640, 256, 17152};

__device__ __forceinline__ void async16(const u16* g, u16* l) {
  __builtin_amdgcn_global_load_lds((const __attribute__((address_space(1))) u32*)g,
                                   (__attribute__((address_space(3))) u32*)l, 16, 0, 0);
}

__global__ __launch_bounds__(512, 2) void conv_gemm(const u16* __restrict__ gp,
                                                    const u16* __restrict__ Bf,
                                                    const float* __restrict__ bc,
                                                    float* __restrict__ out) {
  __shared__ __align__(16) u16 Asm[4][8192];   // 4-stage, 64 KB: 256 rows x 32 ch / stage
  const int bid = blockIdx.x;                  // 256 blocks, 1/CU
  const int id2 = ((bid & 7) << 5) | (bid >> 3);  // XCD x -> images 2x, 2x+1
  const int b   = id2 >> 4;                    // image
  const int y0  = (id2 & 15) << 2;             // 4 y-lines per block (BM=256)

  const int tid  = threadIdx.x;                // 0..511
  const int lane = tid & 63;
  const int wid  = tid >> 6;                   // 0..7
  const int wm   = (wid >> 2) << 7;            // 0 / 128   (2 M-warps)
  const int wn   = (wid & 3) << 6;             // 0/64/128/192 (4 N-warps)
  const int quad = lane >> 4;
  const int r16  = lane & 15;

  // A staging: thread t -> LDS slot t*16B (+4096 elems for rows 128..255);
  // source chunk pre-XORed so linear LDS + swizzled ds_read stays conflict-free.
  const int chunk = (tid & 3) ^ ((tid >> 3) & 3);
  const u16* baseA = gp + ((b * 66 + y0 + 1 + (tid >> 8)) * 66 + ((tid >> 2) & 63) + 1) * 256
                        + (chunk << 3);
  const int ldso = tid * 8;

  // B fragment base: this wave covers o16 = (wn>>4)+nt; per kt stride 8192 u16
  const u16* baseBf = Bf + (wn >> 4) * 512 + lane * 8;

  const int ssl = (quad ^ ((r16 >> 1) & 3)) << 3;

  f32x4 acc[8][4] = {};
  bf16x8 bcur[4], bnxt[4];

  auto issueA = [&](int kt) {                  // DMA 16 KB tile kt into Asm[kt&3]
    const int off = DOFF[kt >> 3] + ((kt & 7) << 5);
    async16(baseA + off,         Asm[kt & 3] + ldso);           // rows 0..127
    async16(baseA + off + 33792, Asm[kt & 3] + 4096 + ldso);    // rows 128..255 (+2 y-lines)
  };
  auto loadB = [&](int kt, bf16x8* dst) {
    const u16* bp = baseBf + (size_t)kt * 8192;
#pragma unroll
    for (int nt = 0; nt < 4; ++nt) dst[nt] = *(const bf16x8*)(bp + nt * 512);
  };
  auto readA = [&](int kt, bf16x8* af) {
    const u16* Ab = Asm[kt & 3];
#pragma unroll
    for (int mt = 0; mt < 8; ++mt)
      af[mt] = *(const bf16x8*)&Ab[(wm + mt * 16 + r16) * 32 + ssl];
  };
  auto domfma = [&](const bf16x8* af, const bf16x8* bb) {
    __builtin_amdgcn_s_setprio(1);
#pragma unroll
    for (int mt = 0; mt < 8; ++mt)
#pragma unroll
      for (int nt = 0; nt < 4; ++nt)
        acc[mt][nt] = __builtin_amdgcn_mfma_f32_16x16x32_bf16(af[mt], bb[nt], acc[mt][nt], 0, 0, 0);
    __builtin_amdgcn_s_setprio(0);
  };

  // prologue: queue = [B(0)x4, A(0)x2, A(1)x2]; vmcnt(2) -> B(0),A(0) done, A(1) flying
  loadB(0, bcur);
  issueA(0);
  issueA(1);
  asm volatile("s_waitcnt vmcnt(2)" ::: "memory");
  asm volatile("s_barrier" ::: "memory");

#pragma unroll 2
  for (int kt = 0; kt < 62; ++kt) {
    loadB(kt + 1, bnxt);                       // issued before this iter's DMA
    bf16x8 af[8];
    readA(kt, af);                             // ds_reads before new DMA (no alias drain)
    issueA(kt + 2);
    domfma(af, bcur);
    // queue: [A(kt+1)x2, B(kt+1)x4, A(kt+2)x2] -> vmcnt(2) retires first 6
    asm volatile("s_waitcnt vmcnt(2)" ::: "memory");
    asm volatile("s_barrier" ::: "memory");
#pragma unroll
    for (int nt = 0; nt < 4; ++nt) bcur[nt] = bnxt[nt];
  }
  // kt = 62: no more A to issue
  {
    loadB(63, bnxt);
    bf16x8 af[8];
    readA(62, af);
    domfma(af, bcur);
    asm volatile("s_waitcnt vmcnt(0)" ::: "memory");
    asm volatile("s_barrier" ::: "memory");
#pragma unroll
    for (int nt = 0; nt < 4; ++nt) bcur[nt] = bnxt[nt];
  }
  // kt = 63
  {
    bf16x8 af[8];
    readA(63, af);
    domfma(af, bcur);
  }

  // epilogue: C/D layout col=lane&15, row=quad*4+reg; block rows = b*4096 + y0*64 + r
  const int pbase = (b * 64 + y0) * 64;
#pragma unroll
  for (int nt = 0; nt < 4; ++nt) {
    const int o = wn + nt * 16 + r16;
    const float bias = bc[o];
#pragma unroll
    for (int mt = 0; mt < 8; ++mt) {
      const int pr = pbase + wm + mt * 16 + quad * 4;
      f32x4 v = acc[mt][nt];
#pragma unroll
      for (int r = 0; r < 4; ++r)
        out[(size_t)(pr + r) * 256 + o] = v[r] + bias;
    }
  }
}

extern "C" void kernel_launch(void* const* d_in, const int* in_sizes, int n_in,
                              void* d_out, int out_size, void* d_ws, size_t ws_size,
                              hipStream_t stream) {
  const float* g  = (const float*)d_in[0];   // [16,64,64,256] f32
  const float* Wd = (const float*)d_in[1];   // [8,256,256]
  const float* Wc = (const float*)d_in[2];   // [256,2048]
  const float* bc = (const float*)d_in[3];   // [256]
  float* out = (float*)d_out;                // [16,64,64,256] f32
  u16* gp = (u16*)d_ws;                            // 35.7 MB padded bf16 input
  u16* Bf = (u16*)((char*)d_ws + GP_BYTES);        // 1 MB fragment-ordered weights

  pad_convert<<<8712, 256, 0, stream>>>(g, gp);
  build_mt<<<32, 256, 0, stream>>>(Wd, Wc, Bf);
  conv_gemm<<<256, 512, 0, stream>>>(gp, Bf, bc, out);
}

// Round 2
// 190.101 us; speedup vs baseline: 1.0594x; 1.0357x over previous
//
#include <hip/hip_runtime.h>

// DirectionalProcessor: out[b,y,x,o] = bc[o] + sum_{d,c} g[b,y-dy_d,x-dx_d,c] * M_d[c,o]
// with M_d[c,o] = sum_e Wd[d,c,e]*Wc[o,d*256+e]  (folded -> 68.7 GFLOP implicit GEMM
// [65536 x 2048] @ [2048 x 256], B,H,W,C=16,64,64,256, 8 dirs).
//
// R7: deep-flight pipeline. R5/R6 both sat at 80 us with every pipe <40% and true
// matrix util ~10% -> loop period was LATENCY-set: vmcnt(2) gave A ~1.3 iters and
// B <1 iter of flight, so each barrier waited on L2/L3-latency loads (Bf thrashed
// out of L2 by the 4.5 MB/XCD A-stream). Now B is DMA'd to LDS like A (per-kt Bf
// slice is 16 KB contiguous = perfect linear global_load_lds), both 4-stage, and
// stage kt+3 is issued each iter (buffer (kt+3)&3=(kt-1)&3 was last read before
// the previous barrier -> safe). FIFO proof: per iter issue [A(kt+3)x2,B(kt+3)x2];
// steady outstanding at the wait = [A(kt+1)x2,B(kt+1)x2 | A(kt+2)x2,B(kt+2)x2 |
// A(kt+3)x2,B(kt+3)x2] = 12; vmcnt(8) retires exactly A/B(kt+1) -> 3-iteration
// flight (>> 900 cy HBM latency). B-register rotation (and its forced-wait hazard)
// is gone; B L2 traffic halves (no 2-wave dup).

typedef unsigned short u16;
typedef unsigned int u32;
typedef __attribute__((ext_vector_type(8))) short bf16x8;   // 8 x bf16 = 4 VGPRs
typedef __attribute__((ext_vector_type(4))) float f32x4;

#define GP_BYTES 35684352    // 16*66*66*256 * 2

__device__ __forceinline__ u16 f2bf(float f) {   // RNE f32->bf16
  u32 u = __float_as_uint(f);
  u32 r = u + 0x7fffu + ((u >> 16) & 1u);
  return (u16)(r >> 16);
}
__device__ __forceinline__ u32 pack2(float a, float b) {
  return (u32)f2bf(a) | ((u32)f2bf(b) << 16);
}

// ---------------- kernel 1: zero-padded bf16 copy of g ----------------
__global__ __launch_bounds__(256) void pad_convert(const float* __restrict__ g,
                                                   u16* __restrict__ gp) {
  int id = blockIdx.x * 256 + threadIdx.x;      // one thread per 8 channels
  if (id >= 2230272) return;                    // 16*66*66*32
  int c8 = id & 31;
  int t = id >> 5;
  int xx = t % 66;
  int s = t / 66;
  int yy = s % 66;
  int b  = s / 66;
  u32 o0 = 0, o1 = 0, o2 = 0, o3 = 0;
  if (yy != 0 && yy != 65 && xx != 0 && xx != 65) {
    const float* src = g + ((((b << 6) + yy - 1) << 6) + xx - 1) * 256 + (c8 << 3);
    float4 fa = *(const float4*)src;
    float4 fb = *(const float4*)(src + 4);
    o0 = pack2(fa.x, fa.y);
    o1 = pack2(fa.z, fa.w);
    o2 = pack2(fb.x, fb.y);
    o3 = pack2(fb.z, fb.w);
  }
  uint4 v; v.x = o0; v.y = o1; v.z = o2; v.w = o3;
  *(uint4*)(gp + (size_t)id * 8) = v;
}

// ---------------- kernel 2: MFMA weight fold into fragment-ordered Bf ----------------
// Bf u16 index: ((d*8 + c32)*16 + o16)*512 + lane*8 + e, where lane = (o&15) + ((c>>3)&3)*16
// holds M_d[c = c32*32 + (lane>>4)*8 + e][o = o16*16 + (lane&15)]  (B-operand frag order).
__global__ __launch_bounds__(256) void build_mt(const float* __restrict__ Wd,
                                                const float* __restrict__ Wc,
                                                u16* __restrict__ Bf) {
  __shared__ __align__(16) u16 As[128 * 32];
  __shared__ __align__(16) u16 Bs[128 * 32];
  const int bid = blockIdx.x;          // 32 blocks: 2 n-tiles x (8 d x 2 c-halves)
  const int n0    = (bid & 1) << 7;
  const int mblk  = bid >> 1;          // 0..15
  const int d     = mblk >> 1;
  const int chalf = (mblk & 1) << 7;
  const int tid  = threadIdx.x;
  const int lane = tid & 63, wid = tid >> 6;
  const int wm = (wid >> 1) << 6, wn = (wid & 1) << 6;
  const int quad = lane >> 4, r16 = lane & 15;
  const int srow = tid >> 1, hh = tid & 1;
  const int swz  = (srow >> 1) & 3;
  const int ssl  = (quad ^ ((r16 >> 1) & 3)) << 3;
  f32x4 acc[4][4] = {};

  for (int e0 = 0; e0 < 256; e0 += 32) {
    __syncthreads();
    const float* pa = Wd + (size_t)(d * 256 + chalf + srow) * 256 + e0 + hh * 16;
    const float* pb = Wc + (size_t)(n0 + srow) * 2048 + d * 256 + e0 + hh * 16;
#pragma unroll
    for (int i = 0; i < 2; ++i) {
      float4 a0 = *(const float4*)(pa + i * 8);
      float4 a1 = *(const float4*)(pa + i * 8 + 4);
      float4 b0 = *(const float4*)(pb + i * 8);
      float4 b1 = *(const float4*)(pb + i * 8 + 4);
      uint4 va, vb;
      va.x = pack2(a0.x, a0.y); va.y = pack2(a0.z, a0.w);
      va.z = pack2(a1.x, a1.y); va.w = pack2(a1.z, a1.w);
      vb.x = pack2(b0.x, b0.y); vb.y = pack2(b0.z, b0.w);
      vb.z = pack2(b1.x, b1.y); vb.w = pack2(b1.z, b1.w);
      int slot = (2 * hh + i) ^ swz;
      *(uint4*)&As[srow * 32 + slot * 8] = va;
      *(uint4*)&Bs[srow * 32 + slot * 8] = vb;
    }
    __syncthreads();
    bf16x8 bfr[4];
#pragma unroll
    for (int nt = 0; nt < 4; ++nt)
      bfr[nt] = *(const bf16x8*)&Bs[(wn + nt * 16 + r16) * 32 + ssl];
#pragma unroll
    for (int mt = 0; mt < 4; ++mt) {
      bf16x8 af = *(const bf16x8*)&As[(wm + mt * 16 + r16) * 32 + ssl];
#pragma unroll
      for (int nt = 0; nt < 4; ++nt)
        acc[mt][nt] = __builtin_amdgcn_mfma_f32_16x16x32_bf16(af, bfr[nt], acc[mt][nt], 0, 0, 0);
    }
  }
  // scatter into fragment-ordered Bf (C/D layout: col=o=r16-based, row=c=quad*4+reg)
#pragma unroll
  for (int mt = 0; mt < 4; ++mt) {
#pragma unroll
    for (int nt = 0; nt < 4; ++nt) {
      const int o = n0 + wn + nt * 16 + r16;
      f32x4 v = acc[mt][nt];
#pragma unroll
      for (int r = 0; r < 4; ++r) {
        const int c = chalf + wm + mt * 16 + quad * 4 + r;
        const int lane2 = (o & 15) + (((c >> 3) & 3) << 4);
        const size_t idx = ((size_t)((d * 8 + (c >> 5)) * 16 + (o >> 4)) * 512) + lane2 * 8 + (c & 7);
        Bf[idx] = f2bf(v[r]);
      }
    }
  }
}

// ---------------- kernel 3: main implicit-GEMM conv ----------------
// directions (dx,dy) -> source offset (ox,oy)=(-dx,-dy); DOFF = (oy*66+ox)*256 in gp elems
__constant__ int DOFF[8] = {16896, 16640, -256, -17152, -16896, -16640, 256, 17152};

__device__ __forceinline__ void async16(const u16* g, u16* l) {
  __builtin_amdgcn_global_load_lds((const __attribute__((address_space(1))) u32*)g,
                                   (__attribute__((address_space(3))) u32*)l, 16, 0, 0);
}

__global__ __launch_bounds__(512, 2) void conv_gemm(const u16* __restrict__ gp,
                                                    const u16* __restrict__ Bf,
                                                    const float* __restrict__ bc,
                                                    float* __restrict__ out) {
  __shared__ __align__(16) u16 Asm[4][8192];   // 4-stage A, 64 KB
  __shared__ __align__(16) u16 Bsm[4][8192];   // 4-stage B, 64 KB
  const int bid = blockIdx.x;                  // 256 blocks, 1/CU
  const int id2 = ((bid & 7) << 5) | (bid >> 3);  // XCD x -> images 2x, 2x+1
  const int b   = id2 >> 4;                    // image
  const int y0  = (id2 & 15) << 2;             // 4 y-lines per block (BM=256)

  const int tid  = threadIdx.x;                // 0..511
  const int lane = tid & 63;
  const int wid  = tid >> 6;                   // 0..7
  const int wm   = (wid >> 2) << 7;            // 0 / 128   (2 M-warps)
  const int wn   = (wid & 3) << 6;             // 0/64/128/192 (4 N-warps)
  const int quad = lane >> 4;
  const int r16  = lane & 15;

  // A staging: thread t -> LDS slot t*16B (+4096 elems for rows 128..255);
  // source chunk pre-XORed so linear LDS + swizzled ds_read stays conflict-free.
  const int chunk = (tid & 3) ^ ((tid >> 3) & 3);
  const u16* baseA = gp + ((b * 66 + y0 + 1 + (tid >> 8)) * 66 + ((tid >> 2) & 63) + 1) * 256
                        + (chunk << 3);
  const int ldso = tid * 8;

  const int ssl = (quad ^ ((r16 >> 1) & 3)) << 3;

  f32x4 acc[8][4] = {};

  auto issueA = [&](int kt) {                  // DMA 16 KB A tile kt into Asm[kt&3]
    const int off = DOFF[kt >> 3] + ((kt & 7) << 5);
    async16(baseA + off,         Asm[kt & 3] + ldso);           // rows 0..127
    async16(baseA + off + 33792, Asm[kt & 3] + 4096 + ldso);    // rows 128..255 (+2 y-lines)
  };
  auto issueB = [&](int kt) {                  // DMA 16 KB Bf slice kt into Bsm[kt&3]
    const u16* src = Bf + (size_t)kt * 8192 + ldso;
    async16(src,        Bsm[kt & 3] + ldso);
    async16(src + 4096, Bsm[kt & 3] + 4096 + ldso);
  };
  auto readA = [&](int kt, bf16x8* af) {
    const u16* Ab = Asm[kt & 3];
#pragma unroll
    for (int mt = 0; mt < 8; ++mt)
      af[mt] = *(const bf16x8*)&Ab[(wm + mt * 16 + r16) * 32 + ssl];
  };
  auto readB = [&](int kt, bf16x8* bb) {       // linear frag reads, lane*16B contiguous
    const u16* Bb = Bsm[kt & 3] + ((wn >> 4) << 9) + lane * 8;
#pragma unroll
    for (int nt = 0; nt < 4; ++nt) bb[nt] = *(const bf16x8*)(Bb + nt * 512);
  };
  auto domfma = [&](const bf16x8* af, const bf16x8* bb) {
    __builtin_amdgcn_s_setprio(1);
#pragma unroll
    for (int mt = 0; mt < 8; ++mt)
#pragma unroll
      for (int nt = 0; nt < 4; ++nt)
        acc[mt][nt] = __builtin_amdgcn_mfma_f32_16x16x32_bf16(af[mt], bb[nt], acc[mt][nt], 0, 0, 0);
    __builtin_amdgcn_s_setprio(0);
  };

  // prologue: FIFO = [A0x2,B0x2, A1x2,B1x2, A2x2,B2x2] (12); vmcnt(8) retires A0,B0
  issueA(0); issueB(0);
  issueA(1); issueB(1);
  issueA(2); issueB(2);
  asm volatile("s_waitcnt vmcnt(8)" ::: "memory");
  asm volatile("s_barrier" ::: "memory");

#pragma unroll 4
  for (int kt = 0; kt < 60; ++kt) {
    bf16x8 bfr[4], af[8];
    readB(kt, bfr);                            // ds_reads before new DMA (no alias drain)
    readA(kt, af);
    issueA(kt + 3);
    issueB(kt + 3);
    domfma(af, bfr);
    // FIFO: [A(kt+1)x2,B(kt+1)x2, A(kt+2)x2,B(kt+2)x2, A(kt+3)x2,B(kt+3)x2]
    // vmcnt(8) retires exactly A/B(kt+1); newest 8 keep flying (3-iter flight)
    asm volatile("s_waitcnt vmcnt(8)" ::: "memory");
    asm volatile("s_barrier" ::: "memory");
  }
  // kt = 60: last iteration that issues (A/B(63))
  {
    bf16x8 bfr[4], af[8];
    readB(60, bfr); readA(60, af);
    issueA(63); issueB(63);
    domfma(af, bfr);
    asm volatile("s_waitcnt vmcnt(8)" ::: "memory");   // retires A/B(61)
    asm volatile("s_barrier" ::: "memory");
  }
  // kt = 61: no more issues; outstanding = [A62x2,B62x2, A63x2,B63x2]
  {
    bf16x8 bfr[4], af[8];
    readB(61, bfr); readA(61, af);
    domfma(af, bfr);
    asm volatile("s_waitcnt vmcnt(4)" ::: "memory");   // retires A/B(62)
    asm volatile("s_barrier" ::: "memory");
  }
  // kt = 62
  {
    bf16x8 bfr[4], af[8];
    readB(62, bfr); readA(62, af);
    domfma(af, bfr);
    asm volatile("s_waitcnt vmcnt(0)" ::: "memory");   // retires A/B(63)
    asm volatile("s_barrier" ::: "memory");
  }
  // kt = 63
  {
    bf16x8 bfr[4], af[8];
    readB(63, bfr); readA(63, af);
    domfma(af, bfr);
  }

  // epilogue: C/D layout col=lane&15, row=quad*4+reg; block rows = b*4096 + y0*64 + r
  const int pbase = (b * 64 + y0) * 64;
#pragma unroll
  for (int nt = 0; nt < 4; ++nt) {
    const int o = wn + nt * 16 + r16;
    const float bias = bc[o];
#pragma unroll
    for (int mt = 0; mt < 8; ++mt) {
      const int pr = pbase + wm + mt * 16 + quad * 4;
      f32x4 v = acc[mt][nt];
#pragma unroll
      for (int r = 0; r < 4; ++r)
        out[(size_t)(pr + r) * 256 + o] = v[r] + bias;
    }
  }
}

extern "C" void kernel_launch(void* const* d_in, const int* in_sizes, int n_in,
                              void* d_out, int out_size, void* d_ws, size_t ws_size,
                              hipStream_t stream) {
  const float* g  = (const float*)d_in[0];   // [16,64,64,256] f32
  const float* Wd = (const float*)d_in[1];   // [8,256,256]
  const float* Wc = (const float*)d_in[2];   // [256,2048]
  const float* bc = (const float*)d_in[3];   // [256]
  float* out = (float*)d_out;                // [16,64,64,256] f32
  u16* gp = (u16*)d_ws;                            // 35.7 MB padded bf16 input
  u16* Bf = (u16*)((char*)d_ws + GP_BYTES);        // 1 MB fragment-ordered weights

  pad_convert<<<8712, 256, 0, stream>>>(g, gp);
  build_mt<<<32, 256, 0, stream>>>(Wd, Wc, Bf);
  conv_gemm<<<256, 512, 0, stream>>>(gp, Bf, bc, out);
}